// Round 6
// baseline (218.615 us; speedup 1.0000x reference)
//
#include <hip/hip_runtime.h>

typedef __bf16 bf16;
typedef __bf16 bf16_4 __attribute__((ext_vector_type(4)));
typedef __bf16 bf16_8 __attribute__((ext_vector_type(8)));
typedef float f32_4 __attribute__((ext_vector_type(4)));

// async global->LDS, 16B per lane; LDS dest must be wave-uniform base + lane*16
#define GLDS16(g, l) \
  __builtin_amdgcn_global_load_lds((const __attribute__((address_space(1))) unsigned int*)(g), \
                                   (__attribute__((address_space(3))) unsigned int*)(l), 16, 0, 0)

// ---------------- fused f32 -> bf16 convert for x + 4 weights ----------------
__global__ __launch_bounds__(256) void convert_all(
    const float* __restrict__ x, const float* __restrict__ wq, const float* __restrict__ wk,
    const float* __restrict__ wv, const float* __restrict__ wo,
    bf16* __restrict__ xb, bf16* __restrict__ wqb, bf16* __restrict__ wkb,
    bf16* __restrict__ wvb, bf16* __restrict__ wob)
{
    int i = blockIdx.x * 256 + threadIdx.x;     // 0 .. 2097151 float4 units
    const float* s; bf16* d; int off;
    if (i < 1048576) { s = x; d = xb; off = i; }
    else {
        int j = i - 1048576;
        int sel = j >> 18;                      // 0..3 (262144 float4 per weight)
        off = j & 262143;
        s = (sel == 0) ? wq : (sel == 1) ? wk : (sel == 2) ? wv : wo;
        d = (sel == 0) ? wqb : (sel == 1) ? wkb : (sel == 2) ? wvb : wob;
    }
    float4 v = reinterpret_cast<const float4*>(s)[off];
    bf16_4 o; o.x = (bf16)v.x; o.y = (bf16)v.y; o.z = (bf16)v.z; o.w = (bf16)v.w;
    reinterpret_cast<bf16_4*>(d)[off] = o;
}

// ---------------- C = A * W^T (+bias) bf16 MFMA GEMM, global_load_lds staging --------
// BK = 64 (128B LDS rows). XOR swizzle: 16B chunk q of row r stored at slot q^(r&7).
// BM = 128: 4 waves 2x2, each 64x64 (acc 4x4).  BM = 64: waves split N, each 64x32 (acc 4x2).
// MODE 0: bf16 out row-major (+bias[n])
// MODE 1: f32 out row-major (+bias[n])
// MODE 5: like 0, but z selects {W,bias,out} (z<2) vs {W2,bias2,out2} (z>=2), batch = z&1
// MODE 6: PV: v *= rsinv[z*2048+m]; bf16 scatter to flat attn: (n>>6)*131072 + m*64 + (n&63)
// MODE 9: scores: e = exp(v*scale - slopes[1]*|m-n|); bf16 e -> outp; row partials -> spart
template<int BM, int MODE>
__global__ __launch_bounds__(256) void gemm_glds(
    const bf16* __restrict__ A, int lda, long long aBatch,
    const bf16* __restrict__ W, int ldw, long long wBatch,
    const float* __restrict__ bias,
    void* __restrict__ outp, long long outBatch,
    int N, int K, float scale, const float* __restrict__ slopes,
    const bf16* __restrict__ W2, const float* __restrict__ bias2, void* __restrict__ out2,
    float* __restrict__ spart, const float* __restrict__ rsinv)
{
    constexpr int CA = BM * 8;                   // A 16B-chunks per tile
    constexpr int NJ = (BM == 128) ? 4 : 2;
    __shared__ alignas(16) bf16 As[BM * 64];
    __shared__ alignas(16) bf16 Bs[128 * 64];

    const int tid  = threadIdx.x;
    const int lane = tid & 63;
    const int wave = tid >> 6;
    const int l15  = lane & 15;
    const int quad = lane >> 4;
    const int m0   = blockIdx.y * BM;
    const int n0   = blockIdx.x * 128;
    const int z    = blockIdx.z;

    const int WM = (BM == 128) ? (wave >> 1) * 64 : 0;
    const int WN = (BM == 128) ? (wave & 1) * 64 : wave * 32;

    const bf16* Ab; const bf16* Wb; const float* bvec; void* op;
    if (MODE == 5) {
        int sel = z >> 1;
        Ab   = A + (long long)(z & 1) * aBatch;
        Wb   = sel ? W2 : W;
        bvec = sel ? bias2 : bias;
        op   = sel ? out2 : outp;
    } else {
        Ab = A + (long long)z * aBatch; Wb = W + (long long)z * wBatch;
        bvec = bias; op = outp;
    }

    f32_4 acc[4][NJ];
#pragma unroll
    for (int i = 0; i < 4; i++)
#pragma unroll
        for (int j = 0; j < NJ; j++) acc[i][j] = (f32_4)(0.0f);

    for (int k0 = 0; k0 < K; k0 += 64) {
        // ---- stage A tile (BM x 64) ----
#pragma unroll
        for (int it = 0; it < CA / 256; ++it) {
            int p = wave * (CA / 4) + it * 64 + lane;
            int r = p >> 3;
            int q = (p & 7) ^ (r & 7);
            GLDS16(Ab + (long long)(m0 + r) * lda + k0 + q * 8, As + p * 8);
        }
        // ---- stage B tile (128 x 64) ----
#pragma unroll
        for (int it = 0; it < 4; ++it) {
            int p = wave * 256 + it * 64 + lane;
            int r = p >> 3;
            int q = (p & 7) ^ (r & 7);
            GLDS16(Wb + (long long)(n0 + r) * ldw + k0 + q * 8, Bs + p * 8);
        }
        __syncthreads();   // drains vmcnt(0) for the glds queue

#pragma unroll
        for (int kh = 0; kh < 2; ++kh) {
            bf16_8 af[4], bfr[NJ];
#pragma unroll
            for (int t = 0; t < 4; ++t) {
                int r = WM + t * 16 + l15;
                int q = (kh * 4 + quad) ^ (r & 7);
                af[t] = *reinterpret_cast<const bf16_8*>(&As[r * 64 + q * 8]);
            }
#pragma unroll
            for (int j = 0; j < NJ; ++j) {
                int r = WN + j * 16 + l15;
                int q = (kh * 4 + quad) ^ (r & 7);
                bfr[j] = *reinterpret_cast<const bf16_8*>(&Bs[r * 64 + q * 8]);
            }
#pragma unroll
            for (int i = 0; i < 4; ++i)
#pragma unroll
                for (int j = 0; j < NJ; ++j)
                    acc[i][j] = __builtin_amdgcn_mfma_f32_16x16x32_bf16(af[i], bfr[j], acc[i][j], 0, 0, 0);
        }
        __syncthreads();   // protect LDS before next iteration's staging
    }

    long long obase = (long long)((MODE == 5) ? (z & 1) : z) * outBatch;

    if constexpr (MODE == 9) {
        const float slope = slopes[1];
#pragma unroll
        for (int i = 0; i < 4; i++) {
#pragma unroll
            for (int rg = 0; rg < 4; rg++) {
                int m = m0 + WM + i * 16 + quad * 4 + rg;
                float rowpart = 0.0f;
#pragma unroll
                for (int j = 0; j < NJ; j++) {
                    int n = n0 + WN + j * 16 + l15;
                    float v = acc[i][j][rg] * scale - slope * fabsf((float)(m - n));
                    float e = __expf(v);
                    rowpart += e;
                    ((bf16*)op)[obase + (long long)m * N + n] = (bf16)e;
                }
                rowpart += __shfl_xor(rowpart, 1, 64);
                rowpart += __shfl_xor(rowpart, 2, 64);
                rowpart += __shfl_xor(rowpart, 4, 64);
                rowpart += __shfl_xor(rowpart, 8, 64);
                if (l15 == 0)
                    spart[((long long)z * 2048 + m) * 32 + (n0 >> 6) + (WN >> 6)] = rowpart;
            }
        }
        return;
    }

#pragma unroll
    for (int i = 0; i < 4; i++) {
#pragma unroll
        for (int j = 0; j < NJ; j++) {
#pragma unroll
            for (int rg = 0; rg < 4; rg++) {
                int m = m0 + WM + i * 16 + quad * 4 + rg;
                int n = n0 + WN + j * 16 + l15;
                float v = acc[i][j][rg];
                if (MODE == 0 || MODE == 5) {
                    if (bvec) v += bvec[n];
                    ((bf16*)op)[obase + (long long)m * N + n] = (bf16)v;
                } else if (MODE == 1) {
                    if (bvec) v += bvec[n];
                    ((float*)op)[obase + (long long)m * N + n] = v;
                } else {  // MODE 6: PV scatter with 1/rowsum scaling
                    v *= rsinv[(long long)z * 2048 + m];
                    long long off = obase +
                                    ((long long)(n >> 6)) * 131072LL + (long long)m * 64 + (n & 63);
                    ((bf16*)op)[off] = (bf16)v;
                }
            }
        }
    }
}

// ---- V transpose with FLAT reshape semantics: vt[b][h*64+d][k] = v_flat[b][h*131072+k*64+d]
__global__ __launch_bounds__(256) void transpose_v(const unsigned short* __restrict__ v,
                                                   unsigned short* __restrict__ vt) {
    __shared__ unsigned short tile[64 * 66];
    const int t  = threadIdx.x;
    const int k0 = blockIdx.x * 64;
    const int h  = blockIdx.y;
    const int b  = blockIdx.z;
    const unsigned short* src = v + (long long)b * 2097152LL + (long long)h * 131072LL;
#pragma unroll
    for (int p = 0; p < 8; p++) {
        int idx = t + p * 256;       // 0..2047
        int k   = idx >> 5;          // 0..63
        int dc  = idx & 31;          // d pair
        ushort2 u = *reinterpret_cast<const ushort2*>(&src[(long long)(k0 + k) * 64 + dc * 2]);
        tile[(dc * 2) * 66 + k]     = u.x;
        tile[(dc * 2 + 1) * 66 + k] = u.y;
    }
    __syncthreads();
    unsigned short* dst = vt + (long long)b * 2097152LL + (long long)h * 64 * 2048LL + k0;
#pragma unroll
    for (int p = 0; p < 8; p++) {
        int idx = t + p * 256;
        int d   = idx >> 5;
        int kc  = idx & 31;
        ushort2 u;
        u.x = tile[d * 66 + kc * 2];
        u.y = tile[d * 66 + kc * 2 + 1];
        *reinterpret_cast<ushort2*>(&dst[(long long)d * 2048 + kc * 2]) = u;
    }
}

// ---------------- normalize: row sums from partials; write probs f32 + inv sums ---------
__global__ __launch_bounds__(256) void normalize_rows(const float* __restrict__ spart,
                                                      const bf16* __restrict__ pb,
                                                      float* __restrict__ probs_f,
                                                      float* __restrict__ rsinv) {
    __shared__ float inv_s;
    const long long row = blockIdx.x;
    const int t = threadIdx.x;

    if (t < 64) {
        float p = (t < 32) ? spart[row * 32 + t] : 0.0f;
#pragma unroll
        for (int o = 1; o <= 32; o <<= 1) p += __shfl_xor(p, o, 64);
        if (t == 0) { float inv = 1.0f / p; inv_s = inv; rsinv[row] = inv; }
    }
    __syncthreads();
    const float inv = inv_s;

    bf16_8 e = reinterpret_cast<const bf16_8*>(pb + row * 2048LL)[t];
    float4 o0, o1;
    o0.x = (float)e[0] * inv; o0.y = (float)e[1] * inv; o0.z = (float)e[2] * inv; o0.w = (float)e[3] * inv;
    o1.x = (float)e[4] * inv; o1.y = (float)e[5] * inv; o1.z = (float)e[6] * inv; o1.w = (float)e[7] * inv;
    reinterpret_cast<float4*>(probs_f + row * 2048LL)[t * 2]     = o0;
    reinterpret_cast<float4*>(probs_f + row * 2048LL)[t * 2 + 1] = o1;
}

// ---------------- launcher ----------------
extern "C" void kernel_launch(void* const* d_in, const int* in_sizes, int n_in,
                              void* d_out, int out_size, void* d_ws, size_t ws_size,
                              hipStream_t stream) {
    const float* x      = (const float*)d_in[0];
    const float* Wq     = (const float*)d_in[1];
    const float* bq     = (const float*)d_in[2];
    const float* Wk     = (const float*)d_in[3];
    const float* bk     = (const float*)d_in[4];
    const float* Wv     = (const float*)d_in[5];
    const float* bv     = (const float*)d_in[6];
    const float* Wo     = (const float*)d_in[7];
    const float* bo     = (const float*)d_in[8];
    const float* slopes = (const float*)d_in[9];

    // B=2, S=2048, E=1024, H=16, hd=64
    char* w = (char*)d_ws;
    bf16* x_bf  = (bf16*)w;  w += 4096LL * 1024 * 2;      // 8.4 MB
    bf16* wq_bf = (bf16*)w;  w += 1024LL * 1024 * 2;
    bf16* wk_bf = (bf16*)w;  w += 1024LL * 1024 * 2;
    bf16* wv_bf = (bf16*)w;  w += 1024LL * 1024 * 2;
    bf16* wo_bf = (bf16*)w;  w += 1024LL * 1024 * 2;
    bf16* qh1   = (bf16*)w;  w += 2LL * 131072 * 2;       // head-1 Q: per b (2048,64) flat
    bf16* kh1   = (bf16*)w;  w += 2LL * 131072 * 2;
    bf16* v_bf  = (bf16*)w;  w += 4096LL * 1024 * 2;      // V proj, row-major
    bf16* vt    = (bf16*)w;  w += 2LL * 1024 * 2048 * 2;  // vt[b][h*64+d][k] (flat reshape!)
    bf16* attn  = (bf16*)w;  w += 4096LL * 1024 * 2;      // flat attn layout
    bf16* pb    = (bf16*)w;  w += 2LL * 2048 * 2048 * 2;  // unnormalized exp, 16.8 MB
    float* spart = (float*)w; w += 4096LL * 32 * 4;       // per-row partial sums
    float* rsinv = (float*)w; w += 4096LL * 4;            // 1/rowsum

    float* out_f   = (float*)d_out;                // (B,S,E)
    float* probs_f = (float*)d_out + 4194304LL;    // (B,1,S,S)

    // 1) all f32->bf16 converts in one launch
    convert_all<<<8192, 256, 0, stream>>>(x, Wq, Wk, Wv, Wo, x_bf, wq_bf, wk_bf, wv_bf, wo_bf);

    // 2) Q & K head-1 projections in one launch: rows 128..255 per batch of x @ {Wq,Wk}^T
    gemm_glds<64, 5><<<dim3(8, 2, 4), 256, 0, stream>>>(
        x_bf + 128LL * 1024, 1024, 2048LL * 1024,
        wq_bf, 1024, 0LL, bq, qh1, 131072LL, 1024, 1024, 1.0f, nullptr,
        wk_bf, bk, kh1, nullptr, nullptr);

    // 3) V projection (full): (4096 x 1024) bf16 row-major
    gemm_glds<64, 0><<<dim3(8, 64, 1), 256, 0, stream>>>(
        x_bf, 1024, 0LL, wv_bf, 1024, 0LL, bv, v_bf, 0LL, 1024, 1024, 1.0f, nullptr,
        nullptr, nullptr, nullptr, nullptr, nullptr);

    // 4) V transpose (flat-reshape mapping) to vt[b][h*64+d][k]
    transpose_v<<<dim3(32, 16, 2), 256, 0, stream>>>((const unsigned short*)v_bf,
                                                     (unsigned short*)vt);

    // 5) scores head-1 + exp + row partials: per b (2048x2048), K=64 -> pb (bf16), spart
    gemm_glds<128, 9><<<dim3(16, 16, 2), 256, 0, stream>>>(
        qh1, 64, 131072LL, kh1, 64, 131072LL, nullptr,
        pb, 4194304LL, 2048, 64, 0.125f, slopes,
        nullptr, nullptr, nullptr, spart, nullptr);

    // 6) normalize: row sums -> rsinv; probs f32 -> d_out
    normalize_rows<<<4096, 256, 0, stream>>>(spart, pb, probs_f, rsinv);

    // 7) PV: per b (2048x1024) = (pb * rsinv) @ vt^T, scatter to flat attn (bf16)
    gemm_glds<64, 6><<<dim3(8, 32, 2), 256, 0, stream>>>(
        pb, 2048, 4194304LL, vt, 2048, 2097152LL, nullptr,
        attn, 2097152LL, 1024, 2048, 1.0f, nullptr,
        nullptr, nullptr, nullptr, nullptr, rsinv);

    // 8) out proj: (4096x1024) f32 = attn @ Wo^T + bo -> d_out   (K=1024)
    gemm_glds<64, 1><<<dim3(8, 64, 1), 256, 0, stream>>>(
        attn, 1024, 0LL, wo_bf, 1024, 0LL, bo,
        out_f, 0LL, 1024, 1024, 1.0f, nullptr,
        nullptr, nullptr, nullptr, nullptr, nullptr);
}

// Round 7
// 195.501 us; speedup vs baseline: 1.1182x; 1.1182x over previous
//
#include <hip/hip_runtime.h>

typedef __bf16 bf16;
typedef __bf16 bf16_4 __attribute__((ext_vector_type(4)));
typedef __bf16 bf16_8 __attribute__((ext_vector_type(8)));
typedef float f32_4 __attribute__((ext_vector_type(4)));

// async global->LDS, 16B per lane; LDS dest must be wave-uniform base + lane*16
#define GLDS16(g, l) \
  __builtin_amdgcn_global_load_lds((const __attribute__((address_space(1))) unsigned int*)(g), \
                                   (__attribute__((address_space(3))) unsigned int*)(l), 16, 0, 0)

// ---------------- fused f32 -> bf16 convert for x + 4 weights ----------------
__global__ __launch_bounds__(256) void convert_all(
    const float* __restrict__ x, const float* __restrict__ wq, const float* __restrict__ wk,
    const float* __restrict__ wv, const float* __restrict__ wo,
    bf16* __restrict__ xb, bf16* __restrict__ wqb, bf16* __restrict__ wkb,
    bf16* __restrict__ wvb, bf16* __restrict__ wob)
{
    int i = blockIdx.x * 256 + threadIdx.x;     // 0 .. 2097151 float4 units
    const float* s; bf16* d; int off;
    if (i < 1048576) { s = x; d = xb; off = i; }
    else {
        int j = i - 1048576;
        int sel = j >> 18;                      // 0..3 (262144 float4 per weight)
        off = j & 262143;
        s = (sel == 0) ? wq : (sel == 1) ? wk : (sel == 2) ? wv : wo;
        d = (sel == 0) ? wqb : (sel == 1) ? wkb : (sel == 2) ? wvb : wob;
    }
    float4 v = reinterpret_cast<const float4*>(s)[off];
    bf16_4 o; o.x = (bf16)v.x; o.y = (bf16)v.y; o.z = (bf16)v.z; o.w = (bf16)v.w;
    reinterpret_cast<bf16_4*>(d)[off] = o;
}

// ---------------- C = A * W^T (+bias) bf16 MFMA GEMM, global_load_lds staging --------
// BK = 64 (128B LDS rows). XOR swizzle: 16B chunk q of row r stored at slot q^(r&7).
// BM = 128: 4 waves 2x2, each 64x64 (acc 4x4).  BM = 64: waves split N, each 64x32 (acc 4x2).
// MODE 1 : f32 out row-major (+bias[n])
// MODE 6 : PV: v *= rsinv[z*2048+m]; bf16 scatter to flat attn: (n>>6)*131072 + m*64 + (n&63)
// MODE 9 : scores: e = exp(v*scale - slopes[1]*|m-n|); bf16 e -> outp; row partials -> spart
// MODE 11: merged projections, role by blockIdx.y:
//          y<64  -> V-proj:  v_bf[m][n] = x@Wv^T + bv   (m = y*64.., all 4096 rows)
//          y>=64 -> QK-proj: sub=y-64: batch=(sub>>1)&1, sel=sub>>2 (0=Q,1=K), m0=(sub&1)*64
//                   rows 128..255 of batch slab of x @ {Wq,Wk}^T + {bq,bk} -> qh1/kh1
template<int BM, int MODE>
__global__ __launch_bounds__(256) void gemm_glds(
    const bf16* __restrict__ A, int lda, long long aBatch,
    const bf16* __restrict__ W, int ldw, long long wBatch,
    const float* __restrict__ bias,
    void* __restrict__ outp, long long outBatch,
    int N, int K, float scale, const float* __restrict__ slopes,
    const bf16* __restrict__ W2, const float* __restrict__ bias2, void* __restrict__ out2,
    const bf16* __restrict__ W3, const float* __restrict__ bias3, void* __restrict__ out3,
    float* __restrict__ spart, const float* __restrict__ rsinv)
{
    constexpr int CA = BM * 8;                   // A 16B-chunks per tile
    constexpr int NJ = (BM == 128) ? 4 : 2;
    __shared__ alignas(16) bf16 As[BM * 64];
    __shared__ alignas(16) bf16 Bs[128 * 64];

    const int tid  = threadIdx.x;
    const int lane = tid & 63;
    const int wave = tid >> 6;
    const int l15  = lane & 15;
    const int quad = lane >> 4;
    const int n0   = blockIdx.x * 128;
    const int z    = blockIdx.z;

    const int WM = (BM == 128) ? (wave >> 1) * 64 : 0;
    const int WN = (BM == 128) ? (wave & 1) * 64 : wave * 32;

    int m0;
    const bf16* Ab; const bf16* Wb; const float* bvec; void* op;
    long long obase;
    if (MODE == 11) {
        int y = blockIdx.y;
        if (y < 64) {            // V role
            m0 = y * 64;
            Ab = A; Wb = W; bvec = bias; op = outp; obase = 0;
        } else {                 // QK role
            int sub   = y - 64;          // 0..7
            int batch = (sub >> 1) & 1;
            int sel   = sub >> 2;        // 0=Q, 1=K
            m0   = (sub & 1) * 64;
            Ab   = A + (long long)batch * 2097152LL + 131072LL;   // rows 128..255 of batch slab
            Wb   = sel ? W3 : W2;
            bvec = sel ? bias3 : bias2;
            op   = sel ? out3 : out2;
            obase = (long long)batch * 131072LL;
        }
    } else {
        m0 = blockIdx.y * BM;
        Ab = A + (long long)z * aBatch; Wb = W + (long long)z * wBatch;
        bvec = bias; op = outp;
        obase = (long long)z * outBatch;
    }

    f32_4 acc[4][NJ];
#pragma unroll
    for (int i = 0; i < 4; i++)
#pragma unroll
        for (int j = 0; j < NJ; j++) acc[i][j] = (f32_4)(0.0f);

    for (int k0 = 0; k0 < K; k0 += 64) {
        // ---- stage A tile (BM x 64) ----
#pragma unroll
        for (int it = 0; it < CA / 256; ++it) {
            int p = wave * (CA / 4) + it * 64 + lane;
            int r = p >> 3;
            int q = (p & 7) ^ (r & 7);
            GLDS16(Ab + (long long)(m0 + r) * lda + k0 + q * 8, As + p * 8);
        }
        // ---- stage B tile (128 x 64) ----
#pragma unroll
        for (int it = 0; it < 4; ++it) {
            int p = wave * 256 + it * 64 + lane;
            int r = p >> 3;
            int q = (p & 7) ^ (r & 7);
            GLDS16(Wb + (long long)(n0 + r) * ldw + k0 + q * 8, Bs + p * 8);
        }
        __syncthreads();   // drains vmcnt(0) for the glds queue

#pragma unroll
        for (int kh = 0; kh < 2; ++kh) {
            bf16_8 af[4], bfr[NJ];
#pragma unroll
            for (int t = 0; t < 4; ++t) {
                int r = WM + t * 16 + l15;
                int q = (kh * 4 + quad) ^ (r & 7);
                af[t] = *reinterpret_cast<const bf16_8*>(&As[r * 64 + q * 8]);
            }
#pragma unroll
            for (int j = 0; j < NJ; ++j) {
                int r = WN + j * 16 + l15;
                int q = (kh * 4 + quad) ^ (r & 7);
                bfr[j] = *reinterpret_cast<const bf16_8*>(&Bs[r * 64 + q * 8]);
            }
#pragma unroll
            for (int i = 0; i < 4; ++i)
#pragma unroll
                for (int j = 0; j < NJ; ++j)
                    acc[i][j] = __builtin_amdgcn_mfma_f32_16x16x32_bf16(af[i], bfr[j], acc[i][j], 0, 0, 0);
        }
        __syncthreads();   // protect LDS before next iteration's staging
    }

    if constexpr (MODE == 9) {
        const float slope = slopes[1];
#pragma unroll
        for (int i = 0; i < 4; i++) {
#pragma unroll
            for (int rg = 0; rg < 4; rg++) {
                int m = m0 + WM + i * 16 + quad * 4 + rg;
                float rowpart = 0.0f;
#pragma unroll
                for (int j = 0; j < NJ; j++) {
                    int n = n0 + WN + j * 16 + l15;
                    float v = acc[i][j][rg] * scale - slope * fabsf((float)(m - n));
                    float e = __expf(v);
                    rowpart += e;
                    ((bf16*)op)[obase + (long long)m * N + n] = (bf16)e;
                }
                rowpart += __shfl_xor(rowpart, 1, 64);
                rowpart += __shfl_xor(rowpart, 2, 64);
                rowpart += __shfl_xor(rowpart, 4, 64);
                rowpart += __shfl_xor(rowpart, 8, 64);
                if (l15 == 0)
                    spart[((long long)z * 2048 + m) * 32 + (n0 >> 6) + (WN >> 6)] = rowpart;
            }
        }
        return;
    }

#pragma unroll
    for (int i = 0; i < 4; i++) {
#pragma unroll
        for (int j = 0; j < NJ; j++) {
#pragma unroll
            for (int rg = 0; rg < 4; rg++) {
                int m = m0 + WM + i * 16 + quad * 4 + rg;
                int n = n0 + WN + j * 16 + l15;
                float v = acc[i][j][rg];
                if (MODE == 11) {
                    v += bvec[n];
                    ((bf16*)op)[obase + (long long)m * 1024 + n] = (bf16)v;
                } else if (MODE == 1) {
                    if (bvec) v += bvec[n];
                    ((float*)op)[obase + (long long)m * N + n] = v;
                } else {  // MODE 6: PV scatter with 1/rowsum scaling
                    v *= rsinv[(long long)z * 2048 + m];
                    long long off = obase +
                                    ((long long)(n >> 6)) * 131072LL + (long long)m * 64 + (n & 63);
                    ((bf16*)op)[off] = (bf16)v;
                }
            }
        }
    }
}

// ---- V transpose with FLAT reshape semantics: vt[b][h*64+d][k] = v_flat[b][h*131072+k*64+d]
__global__ __launch_bounds__(256) void transpose_v(const unsigned short* __restrict__ v,
                                                   unsigned short* __restrict__ vt) {
    __shared__ unsigned short tile[64 * 66];
    const int t  = threadIdx.x;
    const int k0 = blockIdx.x * 64;
    const int h  = blockIdx.y;
    const int b  = blockIdx.z;
    const unsigned short* src = v + (long long)b * 2097152LL + (long long)h * 131072LL;
#pragma unroll
    for (int p = 0; p < 8; p++) {
        int idx = t + p * 256;       // 0..2047
        int k   = idx >> 5;          // 0..63
        int dc  = idx & 31;          // d pair
        ushort2 u = *reinterpret_cast<const ushort2*>(&src[(long long)(k0 + k) * 64 + dc * 2]);
        tile[(dc * 2) * 66 + k]     = u.x;
        tile[(dc * 2 + 1) * 66 + k] = u.y;
    }
    __syncthreads();
    unsigned short* dst = vt + (long long)b * 2097152LL + (long long)h * 64 * 2048LL + k0;
#pragma unroll
    for (int p = 0; p < 8; p++) {
        int idx = t + p * 256;
        int d   = idx >> 5;
        int kc  = idx & 31;
        ushort2 u;
        u.x = tile[d * 66 + kc * 2];
        u.y = tile[d * 66 + kc * 2 + 1];
        *reinterpret_cast<ushort2*>(&dst[(long long)d * 2048 + kc * 2]) = u;
    }
}

// ---------------- normalize: row sums from partials; write probs f32 + inv sums ---------
__global__ __launch_bounds__(256) void normalize_rows(const float* __restrict__ spart,
                                                      const bf16* __restrict__ pb,
                                                      float* __restrict__ probs_f,
                                                      float* __restrict__ rsinv) {
    __shared__ float inv_s;
    const long long row = blockIdx.x;
    const int t = threadIdx.x;

    if (t < 64) {
        float p = (t < 32) ? spart[row * 32 + t] : 0.0f;
#pragma unroll
        for (int o = 1; o <= 32; o <<= 1) p += __shfl_xor(p, o, 64);
        if (t == 0) { float inv = 1.0f / p; inv_s = inv; rsinv[row] = inv; }
    }
    __syncthreads();
    const float inv = inv_s;

    bf16_8 e = reinterpret_cast<const bf16_8*>(pb + row * 2048LL)[t];
    float4 o0, o1;
    o0.x = (float)e[0] * inv; o0.y = (float)e[1] * inv; o0.z = (float)e[2] * inv; o0.w = (float)e[3] * inv;
    o1.x = (float)e[4] * inv; o1.y = (float)e[5] * inv; o1.z = (float)e[6] * inv; o1.w = (float)e[7] * inv;
    reinterpret_cast<float4*>(probs_f + row * 2048LL)[t * 2]     = o0;
    reinterpret_cast<float4*>(probs_f + row * 2048LL)[t * 2 + 1] = o1;
}

// ---------------- launcher ----------------
extern "C" void kernel_launch(void* const* d_in, const int* in_sizes, int n_in,
                              void* d_out, int out_size, void* d_ws, size_t ws_size,
                              hipStream_t stream) {
    const float* x      = (const float*)d_in[0];
    const float* Wq     = (const float*)d_in[1];
    const float* bq     = (const float*)d_in[2];
    const float* Wk     = (const float*)d_in[3];
    const float* bk     = (const float*)d_in[4];
    const float* Wv     = (const float*)d_in[5];
    const float* bv     = (const float*)d_in[6];
    const float* Wo     = (const float*)d_in[7];
    const float* bo     = (const float*)d_in[8];
    const float* slopes = (const float*)d_in[9];

    // B=2, S=2048, E=1024, H=16, hd=64
    char* w = (char*)d_ws;
    bf16* x_bf  = (bf16*)w;  w += 4096LL * 1024 * 2;      // 8.4 MB
    bf16* wq_bf = (bf16*)w;  w += 1024LL * 1024 * 2;
    bf16* wk_bf = (bf16*)w;  w += 1024LL * 1024 * 2;
    bf16* wv_bf = (bf16*)w;  w += 1024LL * 1024 * 2;
    bf16* wo_bf = (bf16*)w;  w += 1024LL * 1024 * 2;
    bf16* qh1   = (bf16*)w;  w += 2LL * 131072 * 2;       // head-1 Q: per b (2048,64) flat
    bf16* kh1   = (bf16*)w;  w += 2LL * 131072 * 2;
    bf16* v_bf  = (bf16*)w;  w += 4096LL * 1024 * 2;      // V proj, row-major
    bf16* vt    = (bf16*)w;  w += 2LL * 1024 * 2048 * 2;  // vt[b][h*64+d][k] (flat reshape!)
    bf16* attn  = (bf16*)w;  w += 4096LL * 1024 * 2;      // flat attn layout
    bf16* pb    = (bf16*)w;  w += 2LL * 2048 * 2048 * 2;  // unnormalized exp, 16.8 MB
    float* spart = (float*)w; w += 4096LL * 32 * 4;       // per-row partial sums
    float* rsinv = (float*)w; w += 4096LL * 4;            // 1/rowsum

    float* out_f   = (float*)d_out;                // (B,S,E)
    float* probs_f = (float*)d_out + 4194304LL;    // (B,1,S,S)

    // 1) all f32->bf16 converts in one launch
    convert_all<<<8192, 256, 0, stream>>>(x, Wq, Wk, Wv, Wo, x_bf, wq_bf, wk_bf, wv_bf, wo_bf);

    // 2) merged projections: V (full 4096x1024) + Q/K head-1 slabs, ONE launch
    gemm_glds<64, 11><<<dim3(8, 72, 1), 256, 0, stream>>>(
        x_bf, 1024, 0LL,
        wv_bf, 1024, 0LL, bv, v_bf, 0LL, 1024, 1024, 1.0f, nullptr,
        wq_bf, bq, qh1,
        wk_bf, bk, kh1,
        nullptr, nullptr);

    // 3) V transpose (flat-reshape mapping) to vt[b][h*64+d][k]
    transpose_v<<<dim3(32, 16, 2), 256, 0, stream>>>((const unsigned short*)v_bf,
                                                     (unsigned short*)vt);

    // 4) scores head-1 + exp + row partials: per b (2048x2048), K=64 -> pb (bf16), spart
    gemm_glds<128, 9><<<dim3(16, 16, 2), 256, 0, stream>>>(
        qh1, 64, 131072LL, kh1, 64, 131072LL, nullptr,
        pb, 4194304LL, 2048, 64, 0.125f, slopes,
        nullptr, nullptr, nullptr, nullptr, nullptr, nullptr, spart, nullptr);

    // 5) normalize: row sums -> rsinv; probs f32 -> d_out
    normalize_rows<<<4096, 256, 0, stream>>>(spart, pb, probs_f, rsinv);

    // 6) PV: per b (2048x1024) = (pb * rsinv) @ vt^T, scatter to flat attn (bf16)
    gemm_glds<64, 6><<<dim3(8, 32, 2), 256, 0, stream>>>(
        pb, 2048, 4194304LL, vt, 2048, 2097152LL, nullptr,
        attn, 2097152LL, 1024, 2048, 1.0f, nullptr,
        nullptr, nullptr, nullptr, nullptr, nullptr, nullptr, nullptr, rsinv);

    // 7) out proj: (4096x1024) f32 = attn @ Wo^T + bo -> d_out   (K=1024)
    gemm_glds<64, 1><<<dim3(8, 64, 1), 256, 0, stream>>>(
        attn, 1024, 0LL, wo_bf, 1024, 0LL, bo,
        out_f, 0LL, 1024, 1024, 1.0f, nullptr,
        nullptr, nullptr, nullptr, nullptr, nullptr, nullptr, nullptr, nullptr);
}